// Round 2
// baseline (2007.643 us; speedup 1.0000x reference)
//
#include <hip/hip_runtime.h>
#include <hip/hip_bf16.h>

// AdaptiveEdgeGAT: N=50000, E=800000, IN=OUT=128, EDGE=64, H=4, D=32
// Dual-mode input read (bf16 or f32, device-detected), f32 accumulation.

#define N_NODES 50000
#define N_EDGES 800000
#define IN_DIM 128
#define OUT_DIM 128
#define EDGE_DIM 64
#define HEADS 4
#define HEAD_DIM 32
#define NEG_SLOPE 0.2f

typedef __hip_bfloat16 bf16;
typedef unsigned short u16;
typedef unsigned int u32;

// canonical f32 weight-block offsets (floats)
#define OFF_WSRC 0
#define OFF_BSRC 16384
#define OFF_WDST 16512
#define OFF_BDST 32896
#define OFF_ATTN 33024
#define OFF_WEDGE 33152
#define OFF_BEDGE 41344
#define OFF_WGATE 41472
#define OFF_BGATE 74240
#define OFF_WOUT 74368
#define OFF_BOUT 90752
#define W_TOTAL 90880

__device__ __forceinline__ float b2f_raw(u16 v) {
    return __uint_as_float(((u32)v) << 16);
}
__device__ __forceinline__ float loadin(const void* p, long i, int isbf) {
    return isbf ? b2f_raw(((const u16*)p)[i]) : ((const float*)p)[i];
}

// order-preserving float->uint encoding for atomicMax on floats
__device__ __forceinline__ unsigned encf(float f) {
    unsigned u = __float_as_uint(f);
    return (u & 0x80000000u) ? ~u : (u | 0x80000000u);
}
__device__ __forceinline__ float decf(unsigned u) {
    unsigned v = (u & 0x80000000u) ? (u & 0x7FFFFFFFu) : ~u;
    return __uint_as_float(v);
}
#define ENC_NEG_INF 0x007FFFFFu  // encf(-inf)

// ---------- dtype detector: read node_feat as bf16; bf16 data is >99% plausible,
// ---------- f32 data read as bf16 is ~53% plausible (odd halves = mantissa bits).
__global__ __launch_bounds__(256) void k_detect(const void* node, int* flag) {
    __shared__ int cnt[256];
    int c = 0;
    for (int i = threadIdx.x; i < 8192; i += 256) {
        float v = b2f_raw(((const u16*)node)[i]);
        float a = fabsf(v);
        if ((a >= 1e-4f && a <= 50.f) || v == 0.f) c++;
    }
    cnt[threadIdx.x] = c;
    __syncthreads();
    for (int s = 128; s > 0; s >>= 1) {
        if (threadIdx.x < s) cnt[threadIdx.x] += cnt[threadIdx.x + s];
        __syncthreads();
    }
    if (threadIdx.x == 0) flag[0] = (cnt[0] >= (8192 * 85) / 100) ? 1 : 0;
}

// ---------- canonicalize all weights/biases into one f32 block ----------
__global__ __launch_bounds__(256) void k_wconv(const void* Wsrc, const void* bsrc,
                                               const void* Wdst, const void* bdst,
                                               const void* attn, const void* Wedge, const void* bedge,
                                               const void* Wgate, const void* bgate,
                                               const void* Wout, const void* bout,
                                               float* w, const int* flag) {
    int i = blockIdx.x * 256 + threadIdx.x;
    if (i >= W_TOTAL) return;
    int f = flag[0];
    const void* p; long off;
    if (i < OFF_BSRC)       { p = Wsrc;  off = i - OFF_WSRC; }
    else if (i < OFF_WDST)  { p = bsrc;  off = i - OFF_BSRC; }
    else if (i < OFF_BDST)  { p = Wdst;  off = i - OFF_WDST; }
    else if (i < OFF_ATTN)  { p = bdst;  off = i - OFF_BDST; }
    else if (i < OFF_WEDGE) { p = attn;  off = i - OFF_ATTN; }
    else if (i < OFF_BEDGE) { p = Wedge; off = i - OFF_WEDGE; }
    else if (i < OFF_WGATE) { p = bedge; off = i - OFF_BEDGE; }
    else if (i < OFF_BGATE) { p = Wgate; off = i - OFF_WGATE; }
    else if (i < OFF_WOUT)  { p = bgate; off = i - OFF_BGATE; }
    else if (i < OFF_BOUT)  { p = Wout;  off = i - OFF_WOUT; }
    else                    { p = bout;  off = i - OFF_BOUT; }
    w[i] = loadin(p, off, f);
}

// ---------- init h_node / m_enc / denom ----------
__global__ __launch_bounds__(256) void k_init(float* __restrict__ h_node,
                                              unsigned* __restrict__ m_enc,
                                              float* __restrict__ denom) {
    int i = blockIdx.x * 256 + threadIdx.x;
    if (i < N_NODES * OUT_DIM) h_node[i] = 0.f;
    if (i < N_NODES * HEADS) { m_enc[i] = ENC_NEG_INF; denom[i] = 0.f; }
}

// ---------- init edge_max (runs after f_src/f_dst are dead; same region) ----------
__global__ __launch_bounds__(256) void k_init_a(unsigned* __restrict__ edge_max_enc) {
    int i = blockIdx.x * 256 + threadIdx.x;
    if (i < N_NODES * OUT_DIM) edge_max_enc[i] = ENC_NEG_INF;
}

// ---------- node projections ----------
#define PROJ_ROWS 16
__global__ __launch_bounds__(128) void k_proj(const void* __restrict__ node,
                                              const float* __restrict__ w, const int* __restrict__ flag,
                                              bf16* __restrict__ f_src, bf16* __restrict__ f_dst) {
    __shared__ float lds[PROJ_ROWS][IN_DIM];
    int isbf = flag[0];
    int col = threadIdx.x;
    long row0 = (long)blockIdx.x * PROJ_ROWS;
    for (int i = col; i < PROJ_ROWS * IN_DIM; i += 128)
        lds[i >> 7][i & 127] = loadin(node, row0 * IN_DIM + i, isbf);
    __syncthreads();
    float accs[PROJ_ROWS], accd[PROJ_ROWS];
    float bsv = w[OFF_BSRC + col], bdv = w[OFF_BDST + col];
#pragma unroll
    for (int r = 0; r < PROJ_ROWS; r++) { accs[r] = bsv; accd[r] = bdv; }
    for (int k = 0; k < IN_DIM; k++) {
        float ws = w[OFF_WSRC + k * OUT_DIM + col];
        float wd = w[OFF_WDST + k * OUT_DIM + col];
#pragma unroll
        for (int r = 0; r < PROJ_ROWS; r++) {
            float x = lds[r][k];
            accs[r] += x * ws;
            accd[r] += x * wd;
        }
    }
#pragma unroll
    for (int r = 0; r < PROJ_ROWS; r++) {
        f_src[(row0 + r) * OUT_DIM + col] = __float2bfloat16(accs[r]);
        f_dst[(row0 + r) * OUT_DIM + col] = __float2bfloat16(accd[r]);
    }
}

// ---------- per-edge GATv2 logits + segment max ----------
__global__ __launch_bounds__(256) void k_logits(const bf16* __restrict__ f_src,
                                                const bf16* __restrict__ f_dst,
                                                const int* __restrict__ src, const int* __restrict__ dst,
                                                const float* __restrict__ w,
                                                bf16* __restrict__ exbuf, unsigned* __restrict__ m_enc) {
    __shared__ float aw[HEADS * HEAD_DIM];
    if (threadIdx.x < HEADS * HEAD_DIM) aw[threadIdx.x] = w[OFF_ATTN + threadIdx.x];
    __syncthreads();
    int t = blockIdx.x * 256 + threadIdx.x;
    int e = t >> 2, h = t & 3;
    if (e >= N_EDGES) return;
    int s = src[e], d = dst[e];
    const bf16* ps = f_src + (long)s * OUT_DIM + h * HEAD_DIM;
    const bf16* pd = f_dst + (long)d * OUT_DIM + h * HEAD_DIM;
    float acc = 0.f;
#pragma unroll
    for (int i = 0; i < HEAD_DIM; i++) {
        float v = __bfloat162float(ps[i]) + __bfloat162float(pd[i]);
        v = v > 0.f ? v : NEG_SLOPE * v;
        acc += v * aw[h * HEAD_DIM + i];
    }
    bf16 lr = __float2bfloat16(acc);
    exbuf[e * HEADS + h] = lr;
    atomicMax(m_enc + (long)d * HEADS + h, encf(__bfloat162float(lr)));
}

// ---------- exp(logit - m) + segment sum ----------
__global__ __launch_bounds__(256) void k_expdenom(const int* __restrict__ dst,
                                                  const unsigned* __restrict__ m_enc,
                                                  bf16* __restrict__ exbuf, float* __restrict__ denom) {
    int t = blockIdx.x * 256 + threadIdx.x;
    if (t >= N_EDGES * HEADS) return;
    int e = t >> 2, h = t & 3;
    int d = dst[e];
    float m = decf(m_enc[(long)d * HEADS + h]);
    float ex = expf(__bfloat162float(exbuf[t]) - m);
    bf16 exb = __float2bfloat16(ex);
    exbuf[t] = exb;
    atomicAdd(denom + (long)d * HEADS + h, __bfloat162float(exb));
}

// ---------- normalize a + scatter weighted messages ----------
__global__ __launch_bounds__(256) void k_scatter_msg(const int* __restrict__ src,
                                                     const int* __restrict__ dst,
                                                     const bf16* __restrict__ f_src,
                                                     const bf16* __restrict__ exbuf,
                                                     const float* __restrict__ denom,
                                                     const int* __restrict__ flag,
                                                     float* __restrict__ h_node,
                                                     bf16* __restrict__ out_a_b, float* __restrict__ out_a_f) {
    long e = (long)blockIdx.x * 2 + (threadIdx.x >> 7);
    int dim = threadIdx.x & 127;
    if (e >= N_EDGES) return;
    int s = src[e], d = dst[e];
    int h = dim >> 5;
    float a = __bfloat162float(exbuf[e * HEADS + h]) / fmaxf(denom[(long)d * HEADS + h], 1e-9f);
    if ((dim & 31) == 0) {
        if (flag[0]) out_a_b[e * HEADS + h] = __float2bfloat16(a);
        else         out_a_f[e * HEADS + h] = a;
    }
    atomicAdd(h_node + (long)d * OUT_DIM + dim, __bfloat162float(f_src[(long)s * OUT_DIM + dim]) * a);
}

// ---------- edge encoder elu(edge @ W_edge + b) + scatter max ----------
__global__ __launch_bounds__(256) void k_edge_enc(const void* __restrict__ edge_feat,
                                                  const int* __restrict__ dst,
                                                  const float* __restrict__ w, const int* __restrict__ flag,
                                                  unsigned* __restrict__ edge_max_enc) {
    __shared__ float elds[2][EDGE_DIM];
    int isbf = flag[0];
    long e0 = (long)blockIdx.x * 2;
    int t = threadIdx.x;
    if (t < 2 * EDGE_DIM) elds[t >> 6][t & 63] = loadin(edge_feat, e0 * EDGE_DIM + t, isbf);
    __syncthreads();
    int el = t >> 7, col = t & 127;
    long e = e0 + el;
    if (e >= N_EDGES) return;
    float acc = w[OFF_BEDGE + col];
#pragma unroll 8
    for (int k = 0; k < EDGE_DIM; k++)
        acc += elds[el][k] * w[OFF_WEDGE + k * OUT_DIM + col];
    float v = acc > 0.f ? acc : expf(acc) - 1.f;  // elu
    atomicMax(edge_max_enc + (long)dst[e] * OUT_DIM + col, encf(v));
}

// ---------- gated fusion (in-place over h_node) ----------
#define GATE_ROWS 8
__global__ __launch_bounds__(128) void k_gate(float* __restrict__ h_node,
                                              const unsigned* __restrict__ edge_max_enc,
                                              const float* __restrict__ w) {
    __shared__ float hn[GATE_ROWS][OUT_DIM];
    __shared__ float em[GATE_ROWS][OUT_DIM];
    int col = threadIdx.x;
    long row0 = (long)blockIdx.x * GATE_ROWS;
    for (int i = col; i < GATE_ROWS * OUT_DIM; i += 128) {
        hn[i >> 7][i & 127] = h_node[row0 * OUT_DIM + i];
        float v = decf(edge_max_enc[row0 * OUT_DIM + i]);
        em[i >> 7][i & 127] = (v < -2.f) ? 0.f : v;  // elu >= -1; sentinel decodes to -inf
    }
    __syncthreads();
    float acc[GATE_ROWS];
    float bg = w[OFF_BGATE + col];
#pragma unroll
    for (int r = 0; r < GATE_ROWS; r++) acc[r] = bg;
    for (int k = 0; k < OUT_DIM; k++) {
        float wv = w[OFF_WGATE + k * OUT_DIM + col];
#pragma unroll
        for (int r = 0; r < GATE_ROWS; r++) acc[r] += hn[r][k] * wv;
    }
    for (int k = 0; k < OUT_DIM; k++) {
        float wv = w[OFF_WGATE + (OUT_DIM + k) * OUT_DIM + col];
#pragma unroll
        for (int r = 0; r < GATE_ROWS; r++) acc[r] += em[r][k] * wv;
    }
#pragma unroll
    for (int r = 0; r < GATE_ROWS; r++) {
        float g = 1.f / (1.f + expf(-acc[r]));
        h_node[(row0 + r) * OUT_DIM + col] = g * hn[r][col] + (1.f - g) * em[r][col];
    }
}

// ---------- output projection ----------
__global__ __launch_bounds__(128) void k_out(const float* __restrict__ h_fused,
                                             const float* __restrict__ w, const int* __restrict__ flag,
                                             bf16* __restrict__ out_b, float* __restrict__ out_f) {
    __shared__ float lds[PROJ_ROWS][OUT_DIM];
    int isbf = flag[0];
    int col = threadIdx.x;
    long row0 = (long)blockIdx.x * PROJ_ROWS;
    for (int i = col; i < PROJ_ROWS * OUT_DIM; i += 128)
        lds[i >> 7][i & 127] = h_fused[row0 * OUT_DIM + i];
    __syncthreads();
    float acc[PROJ_ROWS];
    float bv = w[OFF_BOUT + col];
#pragma unroll
    for (int r = 0; r < PROJ_ROWS; r++) acc[r] = bv;
    for (int k = 0; k < OUT_DIM; k++) {
        float wv = w[OFF_WOUT + k * OUT_DIM + col];
#pragma unroll
        for (int r = 0; r < PROJ_ROWS; r++) acc[r] += lds[r][k] * wv;
    }
#pragma unroll
    for (int r = 0; r < PROJ_ROWS; r++) {
        long idx = (row0 + r) * OUT_DIM + col;
        if (isbf) out_b[idx] = __float2bfloat16(acc[r]);
        else      out_f[idx] = acc[r];
    }
}

extern "C" void kernel_launch(void* const* d_in, const int* in_sizes, int n_in,
                              void* d_out, int out_size, void* d_ws, size_t ws_size,
                              hipStream_t stream) {
    const void* node_feat = d_in[0];
    const void* edge_feat = d_in[1];
    const int* src = (const int*)d_in[2];
    const int* dst = (const int*)d_in[3];

    // workspace layout (bytes), total ~59.6 MB:
    //   0..12.8M   : f_src (bf16)  }  later overlaid by edge_max_enc (u32, 25.6MB)
    //   12.8..25.6M: f_dst (bf16)  }
    //   25.6..32.0M: exbuf (bf16)
    //   32.0..57.6M: h_node (f32)  (becomes h_fused in-place)
    //   57.6..58.4M: m_enc (u32)
    //   58.4..59.2M: denom (f32)
    //   59.2M..    : canonical weights (f32, 363.5KB) + flag (int)
    char* ws = (char*)d_ws;
    bf16* f_src = (bf16*)ws;
    bf16* f_dst = (bf16*)(ws + 12800000);
    unsigned* edge_max_enc = (unsigned*)ws;
    bf16* exbuf = (bf16*)(ws + 25600000);
    float* h_node = (float*)(ws + 32000000);
    unsigned* m_enc = (unsigned*)(ws + 57600000);
    float* denom = (float*)(ws + 58400000);
    float* wcanon = (float*)(ws + 59200000);
    int* flag = (int*)(ws + 59563520);

    bf16* out_b = (bf16*)d_out;
    float* out_f = (float*)d_out;
    bf16* out_a_b = out_b + (size_t)N_NODES * OUT_DIM;
    float* out_a_f = out_f + (size_t)N_NODES * OUT_DIM;

    k_detect<<<1, 256, 0, stream>>>(node_feat, flag);
    k_wconv<<<(W_TOTAL + 255) / 256, 256, 0, stream>>>(d_in[4], d_in[5], d_in[6], d_in[7], d_in[8],
                                                       d_in[9], d_in[10], d_in[11], d_in[12],
                                                       d_in[13], d_in[14], wcanon, flag);
    k_init<<<(N_NODES * OUT_DIM + 255) / 256, 256, 0, stream>>>(h_node, m_enc, denom);
    k_proj<<<N_NODES / PROJ_ROWS, 128, 0, stream>>>(node_feat, wcanon, flag, f_src, f_dst);
    k_logits<<<(N_EDGES * HEADS + 255) / 256, 256, 0, stream>>>(f_src, f_dst, src, dst, wcanon, exbuf, m_enc);
    k_expdenom<<<(N_EDGES * HEADS + 255) / 256, 256, 0, stream>>>(dst, m_enc, exbuf, denom);
    k_scatter_msg<<<N_EDGES / 2, 256, 0, stream>>>(src, dst, f_src, exbuf, denom, flag, h_node, out_a_b, out_a_f);
    k_init_a<<<(N_NODES * OUT_DIM + 255) / 256, 256, 0, stream>>>(edge_max_enc);
    k_edge_enc<<<N_EDGES / 2, 256, 0, stream>>>(edge_feat, dst, wcanon, flag, edge_max_enc);
    k_gate<<<N_NODES / GATE_ROWS, 128, 0, stream>>>(h_node, edge_max_enc, wcanon);
    k_out<<<N_NODES / PROJ_ROWS, 128, 0, stream>>>(h_node, wcanon, flag, out_b, out_f);
}

// Round 3
// 1613.367 us; speedup vs baseline: 1.2444x; 1.2444x over previous
//
#include <hip/hip_runtime.h>
#include <hip/hip_bf16.h>

// AdaptiveEdgeGAT: N=50000, E=800000, IN=OUT=128, EDGE=64, H=4, D=32
// CSR (sort-by-dst) + gather-based segmented reductions: zero data-path atomics.
// Dual-mode input read (bf16 or f32, device-detected), f32 accumulation.

#define N_NODES 50000
#define N_EDGES 800000
#define IN_DIM 128
#define OUT_DIM 128
#define EDGE_DIM 64
#define HEADS 4
#define HEAD_DIM 32
#define NEG_SLOPE 0.2f

typedef __hip_bfloat16 bf16;
typedef unsigned short u16;
typedef unsigned int u32;

// canonical f32 weight-block offsets (floats)
#define OFF_WSRC 0
#define OFF_BSRC 16384
#define OFF_WDST 16512
#define OFF_BDST 32896
#define OFF_ATTN 33024
#define OFF_WEDGE 33152
#define OFF_BEDGE 41344
#define OFF_WGATE 41472
#define OFF_BGATE 74240
#define OFF_WOUT 74368
#define OFF_BOUT 90752
#define OFF_WEDGE_T 90880   // transposed W_edge: [col][k] = [128][64]
#define W_TOTAL 99072

__device__ __forceinline__ float b2f_raw(u16 v) {
    return __uint_as_float(((u32)v) << 16);
}
__device__ __forceinline__ float b2f(bf16 v) { return __bfloat162float(v); }
__device__ __forceinline__ float loadin(const void* p, long i, int isbf) {
    return isbf ? b2f_raw(((const u16*)p)[i]) : ((const float*)p)[i];
}

// ---------- dtype detector ----------
__global__ __launch_bounds__(256) void k_detect(const void* node, int* flag) {
    __shared__ int cnt[256];
    int c = 0;
    for (int i = threadIdx.x; i < 8192; i += 256) {
        float v = b2f_raw(((const u16*)node)[i]);
        float a = fabsf(v);
        if ((a >= 1e-4f && a <= 50.f) || v == 0.f) c++;
    }
    cnt[threadIdx.x] = c;
    __syncthreads();
    for (int s = 128; s > 0; s >>= 1) {
        if (threadIdx.x < s) cnt[threadIdx.x] += cnt[threadIdx.x + s];
        __syncthreads();
    }
    if (threadIdx.x == 0) flag[0] = (cnt[0] >= (8192 * 85) / 100) ? 1 : 0;
}

// ---------- canonicalize weights to f32 (+ transposed W_edge) ----------
__global__ __launch_bounds__(256) void k_wconv(const void* Wsrc, const void* bsrc,
                                               const void* Wdst, const void* bdst,
                                               const void* attn, const void* Wedge, const void* bedge,
                                               const void* Wgate, const void* bgate,
                                               const void* Wout, const void* bout,
                                               float* w, const int* flag) {
    int i = blockIdx.x * 256 + threadIdx.x;
    if (i >= W_TOTAL) return;
    int f = flag[0];
    const void* p; long off;
    if (i < OFF_BSRC)         { p = Wsrc;  off = i - OFF_WSRC; }
    else if (i < OFF_WDST)    { p = bsrc;  off = i - OFF_BSRC; }
    else if (i < OFF_BDST)    { p = Wdst;  off = i - OFF_WDST; }
    else if (i < OFF_ATTN)    { p = bdst;  off = i - OFF_BDST; }
    else if (i < OFF_WEDGE)   { p = attn;  off = i - OFF_ATTN; }
    else if (i < OFF_BEDGE)   { p = Wedge; off = i - OFF_WEDGE; }
    else if (i < OFF_WGATE)   { p = bedge; off = i - OFF_BEDGE; }
    else if (i < OFF_BGATE)   { p = Wgate; off = i - OFF_WGATE; }
    else if (i < OFF_WOUT)    { p = bgate; off = i - OFF_BGATE; }
    else if (i < OFF_BOUT)    { p = Wout;  off = i - OFF_WOUT; }
    else if (i < OFF_WEDGE_T) { p = bout;  off = i - OFF_BOUT; }
    else { // transposed W_edge: wt[col*64+k] = W_edge[k*128+col]
        int idx = i - OFF_WEDGE_T;
        int col = idx >> 6, k = idx & 63;
        w[i] = loadin(Wedge, (long)k * OUT_DIM + col, f);
        return;
    }
    w[i] = loadin(p, off, f);
}

// ---------- zero degree counters ----------
__global__ __launch_bounds__(256) void k_zero(int* __restrict__ deg) {
    int i = blockIdx.x * 256 + threadIdx.x;
    if (i < N_NODES) deg[i] = 0;
}

// ---------- degree histogram ----------
__global__ __launch_bounds__(256) void k_hist(const int* __restrict__ dst, int* __restrict__ deg) {
    int e = blockIdx.x * 256 + threadIdx.x;
    if (e < N_EDGES) atomicAdd(&deg[dst[e]], 1);
}

// ---------- exclusive prefix sum (single block) -> rowptr, cursor ----------
__global__ __launch_bounds__(1024) void k_scan(const int* __restrict__ deg,
                                               int* __restrict__ rowptr,
                                               int* __restrict__ cursor) {
    __shared__ int buf[1024];
    __shared__ int carry;
    int tid = threadIdx.x;
    if (tid == 0) carry = 0;
    __syncthreads();
    for (int base = 0; base <= N_NODES; base += 1024) {
        int i = base + tid;
        int v = (i < N_NODES) ? deg[i] : 0;
        buf[tid] = v;
        __syncthreads();
        for (int s = 1; s < 1024; s <<= 1) {
            int add = (tid >= s) ? buf[tid - s] : 0;
            __syncthreads();
            buf[tid] += add;
            __syncthreads();
        }
        int excl = carry + buf[tid] - v;
        if (i <= N_NODES) {
            rowptr[i] = excl;
            if (i < N_NODES) cursor[i] = excl;
        }
        __syncthreads();
        if (tid == 1023) carry += buf[1023];
        __syncthreads();
    }
}

// ---------- scatter edge ids into dst-sorted order ----------
__global__ __launch_bounds__(256) void k_permute(const int* __restrict__ dst,
                                                 int* __restrict__ cursor, int* __restrict__ perm) {
    int e = blockIdx.x * 256 + threadIdx.x;
    if (e >= N_EDGES) return;
    int p = atomicAdd(&cursor[dst[e]], 1);
    perm[p] = e;
}

// ---------- node projections ----------
#define PROJ_ROWS 16
__global__ __launch_bounds__(128) void k_proj(const void* __restrict__ node,
                                              const float* __restrict__ w, const int* __restrict__ flag,
                                              bf16* __restrict__ f_src, bf16* __restrict__ f_dst) {
    __shared__ float lds[PROJ_ROWS][IN_DIM];
    int isbf = flag[0];
    int col = threadIdx.x;
    long row0 = (long)blockIdx.x * PROJ_ROWS;
    for (int i = col; i < PROJ_ROWS * IN_DIM; i += 128)
        lds[i >> 7][i & 127] = loadin(node, row0 * IN_DIM + i, isbf);
    __syncthreads();
    float accs[PROJ_ROWS], accd[PROJ_ROWS];
    float bsv = w[OFF_BSRC + col], bdv = w[OFF_BDST + col];
#pragma unroll
    for (int r = 0; r < PROJ_ROWS; r++) { accs[r] = bsv; accd[r] = bdv; }
    for (int k = 0; k < IN_DIM; k++) {
        float ws = w[OFF_WSRC + k * OUT_DIM + col];
        float wd = w[OFF_WDST + k * OUT_DIM + col];
#pragma unroll
        for (int r = 0; r < PROJ_ROWS; r++) {
            float x = lds[r][k];
            accs[r] += x * ws;
            accd[r] += x * wd;
        }
    }
#pragma unroll
    for (int r = 0; r < PROJ_ROWS; r++) {
        f_src[(row0 + r) * OUT_DIM + col] = __float2bfloat16(accs[r]);
        f_dst[(row0 + r) * OUT_DIM + col] = __float2bfloat16(accd[r]);
    }
}

// ---------- per-edge GATv2 logits (no atomics) ----------
__global__ __launch_bounds__(256) void k_logits(const bf16* __restrict__ f_src,
                                                const bf16* __restrict__ f_dst,
                                                const int* __restrict__ src, const int* __restrict__ dst,
                                                const float* __restrict__ w,
                                                bf16* __restrict__ logits) {
    __shared__ float aw[HEADS * HEAD_DIM];
    if (threadIdx.x < HEADS * HEAD_DIM) aw[threadIdx.x] = w[OFF_ATTN + threadIdx.x];
    __syncthreads();
    int t = blockIdx.x * 256 + threadIdx.x;
    int e = t >> 2, h = t & 3;
    if (e >= N_EDGES) return;
    int s = src[e], d = dst[e];
    const bf16* ps = f_src + (long)s * OUT_DIM + h * HEAD_DIM;
    const bf16* pd = f_dst + (long)d * OUT_DIM + h * HEAD_DIM;
    float acc = 0.f;
#pragma unroll
    for (int i = 0; i < HEAD_DIM; i++) {
        float v = b2f(ps[i]) + b2f(pd[i]);
        v = v > 0.f ? v : NEG_SLOPE * v;
        acc += v * aw[h * HEAD_DIM + i];
    }
    logits[(long)e * HEADS + h] = __float2bfloat16(acc);
}

// ---------- per-node aggregation: softmax + msg gather + edge GEMM + max ----------
#define CAP 512
__global__ __launch_bounds__(128) void k_node_agg(const int* __restrict__ rowptr,
                                                  const int* __restrict__ perm,
                                                  const int* __restrict__ src,
                                                  const bf16* __restrict__ f_src,
                                                  const bf16* __restrict__ logits,
                                                  const void* __restrict__ edge_feat,
                                                  const float* __restrict__ w, const int* __restrict__ flag,
                                                  bf16* __restrict__ h_node, bf16* __restrict__ edge_max,
                                                  bf16* __restrict__ out_a_b, float* __restrict__ out_a_f) {
    __shared__ int eidx[CAP];
    __shared__ int esrc[CAP];
    __shared__ u16 elog[CAP][4];
    __shared__ float xrow[4][EDGE_DIM];
    int n = blockIdx.x;
    int tid = threadIdx.x;
    int col = tid;
    int h = tid >> 5;            // head for this lane's column group
    int isbf = flag[0];
    int r0 = rowptr[n], r1 = rowptr[n + 1];
    int deg = r1 - r0;
    int capn = deg < CAP ? deg : CAP;

    for (int j = tid; j < capn; j += 128) {
        int e = perm[r0 + j];
        eidx[j] = e;
        esrc[j] = src[e];
        ((uint2*)&elog[j][0])[0] = ((const uint2*)logits)[e];
    }
    __syncthreads();

    // --- softmax stats per head (lanes grouped by 32) ---
    float mloc = -3.0e38f;
    for (int j = tid & 31; j < deg; j += 32) {
        float lg = (j < CAP) ? b2f_raw(elog[j][h])
                             : b2f_raw(((const u16*)logits)[(long)perm[r0 + j] * HEADS + h]);
        mloc = fmaxf(mloc, lg);
    }
#pragma unroll
    for (int m = 16; m; m >>= 1) mloc = fmaxf(mloc, __shfl_xor(mloc, m, 32));
    float sloc = 0.f;
    for (int j = tid & 31; j < deg; j += 32) {
        float lg = (j < CAP) ? b2f_raw(elog[j][h])
                             : b2f_raw(((const u16*)logits)[(long)perm[r0 + j] * HEADS + h]);
        sloc += expf(lg - mloc);
    }
#pragma unroll
    for (int m = 16; m; m >>= 1) sloc += __shfl_xor(sloc, m, 32);
    float inv = 1.f / fmaxf(sloc, 1e-9f);

    // --- message gather + out_a writes ---
    float accm = 0.f;
    for (int j = 0; j < deg; j++) {
        int e, s; float lg;
        if (j < CAP) { e = eidx[j]; s = esrc[j]; lg = b2f_raw(elog[j][h]); }
        else { e = perm[r0 + j]; s = src[e]; lg = b2f_raw(((const u16*)logits)[(long)e * HEADS + h]); }
        float aj = expf(lg - mloc) * inv;
        accm += b2f(f_src[(long)s * OUT_DIM + col]) * aj;
        if ((col & 31) == 0) {
            if (isbf) out_a_b[(long)e * HEADS + h] = __float2bfloat16(aj);
            else      out_a_f[(long)e * HEADS + h] = aj;
        }
    }
    h_node[(long)n * OUT_DIM + col] = __float2bfloat16(accm);

    // --- edge encoder GEMM (4 edges/group) + running max ---
    float vmax = -3.0e38f;
    const float4* wt4 = (const float4*)(w + OFF_WEDGE_T + col * EDGE_DIM);
    float bias = w[OFF_BEDGE + col];
    for (int g0 = 0; g0 < deg; g0 += 4) {
        int nr = deg - g0; if (nr > 4) nr = 4;
        __syncthreads();  // previous iteration's xrow reads done
        for (int idx = tid; idx < 128; idx += 128) {
            int r = idx >> 5, kk = idx & 31;   // kk indexes element pairs
            float v0 = 0.f, v1 = 0.f;
            if (r < nr) {
                long e = (g0 + r < CAP) ? eidx[g0 + r] : perm[r0 + g0 + r];
                if (isbf) {
                    u32 pp = ((const u32*)edge_feat)[e * (EDGE_DIM / 2) + kk];
                    v0 = b2f_raw((u16)(pp & 0xFFFF));
                    v1 = b2f_raw((u16)(pp >> 16));
                } else {
                    float2 pf = ((const float2*)edge_feat)[e * (EDGE_DIM / 2) + kk];
                    v0 = pf.x; v1 = pf.y;
                }
            }
            xrow[r][kk * 2] = v0;
            xrow[r][kk * 2 + 1] = v1;
        }
        __syncthreads();
        float a0 = bias, a1 = bias, a2 = bias, a3 = bias;
#pragma unroll
        for (int kk = 0; kk < EDGE_DIM / 4; kk++) {
            float4 wv = wt4[kk];
            float4 x0 = ((const float4*)xrow[0])[kk];
            float4 x1 = ((const float4*)xrow[1])[kk];
            float4 x2 = ((const float4*)xrow[2])[kk];
            float4 x3 = ((const float4*)xrow[3])[kk];
            a0 += x0.x * wv.x + x0.y * wv.y + x0.z * wv.z + x0.w * wv.w;
            a1 += x1.x * wv.x + x1.y * wv.y + x1.z * wv.z + x1.w * wv.w;
            a2 += x2.x * wv.x + x2.y * wv.y + x2.z * wv.z + x2.w * wv.w;
            a3 += x3.x * wv.x + x3.y * wv.y + x3.z * wv.z + x3.w * wv.w;
        }
        if (nr > 0) vmax = fmaxf(vmax, a0 > 0.f ? a0 : expf(a0) - 1.f);
        if (nr > 1) vmax = fmaxf(vmax, a1 > 0.f ? a1 : expf(a1) - 1.f);
        if (nr > 2) vmax = fmaxf(vmax, a2 > 0.f ? a2 : expf(a2) - 1.f);
        if (nr > 3) vmax = fmaxf(vmax, a3 > 0.f ? a3 : expf(a3) - 1.f);
    }
    edge_max[(long)n * OUT_DIM + col] = __float2bfloat16(deg > 0 ? vmax : 0.f);
}

// ---------- gated fusion (in-place over h_node) ----------
#define GATE_ROWS 8
__global__ __launch_bounds__(128) void k_gate(bf16* __restrict__ h_node,
                                              const bf16* __restrict__ edge_max,
                                              const float* __restrict__ w) {
    __shared__ float hn[GATE_ROWS][OUT_DIM];
    __shared__ float em[GATE_ROWS][OUT_DIM];
    int col = threadIdx.x;
    long row0 = (long)blockIdx.x * GATE_ROWS;
    for (int i = col; i < GATE_ROWS * OUT_DIM; i += 128) {
        hn[i >> 7][i & 127] = b2f(h_node[row0 * OUT_DIM + i]);
        em[i >> 7][i & 127] = b2f(edge_max[row0 * OUT_DIM + i]);
    }
    __syncthreads();
    float acc[GATE_ROWS];
    float bg = w[OFF_BGATE + col];
#pragma unroll
    for (int r = 0; r < GATE_ROWS; r++) acc[r] = bg;
    for (int k = 0; k < OUT_DIM; k++) {
        float wv = w[OFF_WGATE + k * OUT_DIM + col];
#pragma unroll
        for (int r = 0; r < GATE_ROWS; r++) acc[r] += hn[r][k] * wv;
    }
    for (int k = 0; k < OUT_DIM; k++) {
        float wv = w[OFF_WGATE + (OUT_DIM + k) * OUT_DIM + col];
#pragma unroll
        for (int r = 0; r < GATE_ROWS; r++) acc[r] += em[r][k] * wv;
    }
#pragma unroll
    for (int r = 0; r < GATE_ROWS; r++) {
        float g = 1.f / (1.f + expf(-acc[r]));
        h_node[(row0 + r) * OUT_DIM + col] = __float2bfloat16(g * hn[r][col] + (1.f - g) * em[r][col]);
    }
}

// ---------- output projection ----------
__global__ __launch_bounds__(128) void k_out(const bf16* __restrict__ h_fused,
                                             const float* __restrict__ w, const int* __restrict__ flag,
                                             bf16* __restrict__ out_b, float* __restrict__ out_f) {
    __shared__ float lds[PROJ_ROWS][OUT_DIM];
    int isbf = flag[0];
    int col = threadIdx.x;
    long row0 = (long)blockIdx.x * PROJ_ROWS;
    for (int i = col; i < PROJ_ROWS * OUT_DIM; i += 128)
        lds[i >> 7][i & 127] = b2f(h_fused[row0 * OUT_DIM + i]);
    __syncthreads();
    float acc[PROJ_ROWS];
    float bv = w[OFF_BOUT + col];
#pragma unroll
    for (int r = 0; r < PROJ_ROWS; r++) acc[r] = bv;
    for (int k = 0; k < OUT_DIM; k++) {
        float wv = w[OFF_WOUT + k * OUT_DIM + col];
#pragma unroll
        for (int r = 0; r < PROJ_ROWS; r++) acc[r] += lds[r][k] * wv;
    }
#pragma unroll
    for (int r = 0; r < PROJ_ROWS; r++) {
        long idx = (row0 + r) * OUT_DIM + col;
        if (isbf) out_b[idx] = __float2bfloat16(acc[r]);
        else      out_f[idx] = acc[r];
    }
}

extern "C" void kernel_launch(void* const* d_in, const int* in_sizes, int n_in,
                              void* d_out, int out_size, void* d_ws, size_t ws_size,
                              hipStream_t stream) {
    const void* node_feat = d_in[0];
    const void* edge_feat = d_in[1];
    const int* src = (const int*)d_in[2];
    const int* dst = (const int*)d_in[3];

    // workspace layout (bytes), total ~49.0 MB (proven-safe < 59.6 MB):
    //   0        .. 12.8M : f_src   bf16 [N][128]
    //   12.8M    .. 25.6M : f_dst   bf16 [N][128]  -> overlaid by edge_max bf16 after k_logits
    //   25.6M    .. 32.0M : logits  bf16 [E][4]
    //   32.0M    .. 44.8M : h_node  bf16 [N][128]  (h_fused in-place)
    //   44.8M    ..       : deg, rowptr, cursor, perm, wcanon, flag
    char* ws = (char*)d_ws;
    bf16* f_src = (bf16*)ws;
    bf16* f_dst = (bf16*)(ws + 12800000);
    bf16* edge_max = (bf16*)(ws + 12800000);  // overlays f_dst (dead after k_logits)
    bf16* logits = (bf16*)(ws + 25600000);
    bf16* h_node = (bf16*)(ws + 32000000);
    int* deg = (int*)(ws + 44800000);
    int* rowptr = (int*)(ws + 45000000);
    int* cursor = (int*)(ws + 45200008);
    int* perm = (int*)(ws + 45400016);
    float* wcanon = (float*)(ws + 48600032);
    int* flag = (int*)(ws + 48996320);

    bf16* out_b = (bf16*)d_out;
    float* out_f = (float*)d_out;
    bf16* out_a_b = out_b + (size_t)N_NODES * OUT_DIM;
    float* out_a_f = out_f + (size_t)N_NODES * OUT_DIM;

    k_detect<<<1, 256, 0, stream>>>(node_feat, flag);
    k_wconv<<<(W_TOTAL + 255) / 256, 256, 0, stream>>>(d_in[4], d_in[5], d_in[6], d_in[7], d_in[8],
                                                       d_in[9], d_in[10], d_in[11], d_in[12],
                                                       d_in[13], d_in[14], wcanon, flag);
    k_zero<<<(N_NODES + 255) / 256, 256, 0, stream>>>(deg);
    k_hist<<<(N_EDGES + 255) / 256, 256, 0, stream>>>(dst, deg);
    k_scan<<<1, 1024, 0, stream>>>(deg, rowptr, cursor);
    k_permute<<<(N_EDGES + 255) / 256, 256, 0, stream>>>(dst, cursor, perm);
    k_proj<<<N_NODES / PROJ_ROWS, 128, 0, stream>>>(node_feat, wcanon, flag, f_src, f_dst);
    k_logits<<<(N_EDGES * HEADS + 255) / 256, 256, 0, stream>>>(f_src, f_dst, src, dst, wcanon, logits);
    k_node_agg<<<N_NODES, 128, 0, stream>>>(rowptr, perm, src, f_src, logits, edge_feat,
                                            wcanon, flag, h_node, edge_max, out_a_b, out_a_f);
    k_gate<<<N_NODES / GATE_ROWS, 128, 0, stream>>>(h_node, edge_max, wcanon);
    k_out<<<N_NODES / PROJ_ROWS, 128, 0, stream>>>(h_node, wcanon, flag, out_b, out_f);
}